// Round 10
// baseline (646.940 us; speedup 1.0000x reference)
//
#include <hip/hip_runtime.h>
#include <math.h>

#define CDIM 192
#define NHEADS 6
#define HDIM 32
#define WSZ 7
#define NTOK 49
#define SHIFT 3
#define HW 56
#define MLPH 768
#define NTOKENS 100352   // 32*56*56
#define QKS 576          // qkvg row stride (q|k|v each 192)
// attn kernel strides (bf16 elems unless noted)
#define XS 200   // s_o row stride
#define VTS 72   // s_vt row stride (192 rows)
#define PPS 72   // s_P row stride (8 wave slabs x 16 rows)
#define LS 196   // s_ln row stride (fp32)
// fused-fallback strides
#define QPS 72
// mlp kernel strides
#define AS2 200  // s_a row stride (bf16)
#define HS2 200  // s_h chunk row stride (bf16, 192 cols)
#define OS2 196  // s_o row stride (fp32)

typedef __attribute__((ext_vector_type(8))) short short8;
typedef __attribute__((ext_vector_type(4))) float floatx4;
typedef unsigned short ushort_t;
typedef unsigned int uint_t;

// float -> bf16 RNE via native cast: clang emits hardware cvt (pairs fuse to
// v_cvt_pk_bf16_f32).
__device__ __forceinline__ ushort_t f2b(float f) {
  __bf16 b = (__bf16)f;
  return __builtin_bit_cast(ushort_t, b);
}

// gelu tanh-form: max dev from exact-erf gelu ~3e-4, below bf16 rounding.
__device__ __forceinline__ float gelu_fast(float v) {
  float u2 = 1.5957691f * v * (1.0f + 0.044715f * v * v);
  float s = 1.0f / (1.0f + __expf(-u2));
  return v * s;
}

// ---------------------------------------------------------------------------
// Prep: convert fc1_w, fc2_w, qkv_w, proj_w to bf16 in workspace.
// pwb columns are PERMUTED within each 32-wide head block to match qkvg's
// pair-interleaved channel layout (pos(d) = d<16 ? 2d : 2(d-16)+1): proj's
// K-axis dot product is invariant under a shared permutation.
// ---------------------------------------------------------------------------
__global__ void prep_kernel(const float* __restrict__ fc1_w, const float* __restrict__ fc2_w,
                            const float* __restrict__ qkv_w, const float* __restrict__ proj_w,
                            ushort_t* __restrict__ w1b, ushort_t* __restrict__ w2b,
                            ushort_t* __restrict__ qwb, ushort_t* __restrict__ pwb) {
  int i = blockIdx.x * 256 + threadIdx.x;
  if (i < MLPH*CDIM) w1b[i] = f2b(fc1_w[i]);
  else if (i < 2*MLPH*CDIM) w2b[i - MLPH*CDIM] = f2b(fc2_w[i - MLPH*CDIM]);
  else if (i < 2*MLPH*CDIM + 3*CDIM*CDIM) qwb[i - 2*MLPH*CDIM] = f2b(qkv_w[i - 2*MLPH*CDIM]);
  else if (i < 2*MLPH*CDIM + 4*CDIM*CDIM) {
    int j = i - 2*MLPH*CDIM - 3*CDIM*CDIM;
    int n = j / CDIM, k = j % CDIM;
    int h = k / 32, kloc = k % 32;
    int pos = (kloc < 16) ? 2*kloc : 2*(kloc-16) + 1;
    pwb[n*CDIM + h*32 + pos] = f2b(proj_w[j]);
  }
}

// ---------------------------------------------------------------------------
// CPB MLP stage 1: bias table (169 x 6). One wave per table entry.
// ---------------------------------------------------------------------------
__global__ __launch_bounds__(256) void cpb1_kernel(const float* __restrict__ w1,
                                                   const float* __restrict__ b1,
                                                   const float* __restrict__ w2,
                                                   float* __restrict__ bt) {
  int wave = threadIdx.x >> 6, lane = threadIdx.x & 63;
  int e = blockIdx.x * 4 + wave;
  if (e >= 169) return;
  const float inv_log2_7 = 0.35620718710802217f;
  int a = e / 13, b = e % 13;
  float v0 = (float)(a - 6) * (7.0f / 6.0f);
  float v1 = (float)(b - 6) * (7.0f / 6.0f);
  float s0 = (v0 > 0.f) ? 1.f : ((v0 < 0.f) ? -1.f : 0.f);
  float s1 = (v1 > 0.f) ? 1.f : ((v1 < 0.f) ? -1.f : 0.f);
  v0 = s0 * log2f(fabsf(v0) + 1.0f) * inv_log2_7;
  v1 = s1 * log2f(fabsf(v1) + 1.0f) * inv_log2_7;
  float acc[NHEADS];
  #pragma unroll
  for (int h = 0; h < NHEADS; ++h) acc[h] = 0.f;
  #pragma unroll
  for (int j = 0; j < 8; ++j) {
    int k = lane + 64*j;
    float hv = v0 * w1[2*k] + v1 * w1[2*k+1] + b1[k];
    hv = (hv > 0.f) ? hv : 0.01f * hv;
    #pragma unroll
    for (int h = 0; h < NHEADS; ++h) acc[h] += hv * w2[h*512 + k];
  }
  #pragma unroll
  for (int m = 1; m < 64; m <<= 1)
    #pragma unroll
    for (int h = 0; h < NHEADS; ++h) acc[h] += __shfl_xor(acc[h], m, 64);
  if (lane == 0) {
    #pragma unroll
    for (int h = 0; h < NHEADS; ++h) bt[e*NHEADS + h] = acc[h];
  }
}

// CPB stage 2: expand to cbias[4 cls][6][49][49] = 14*sigmoid(bias) - 100*mask.
__global__ void cpb2_kernel(const float* __restrict__ bt, float* __restrict__ cbias) {
  int e = blockIdx.x * 256 + threadIdx.x;
  if (e >= 4*NHEADS*NTOK*NTOK) return;
  int cls = e / (NHEADS*NTOK*NTOK);
  int rem = e % (NHEADS*NTOK*NTOK);
  int h = rem / (NTOK*NTOK);
  int r = rem % (NTOK*NTOK);
  int i = r / NTOK, j = r % NTOK;
  int idx = (i/7 - j/7 + 6) * 13 + (i%7 - j%7 + 6);
  float v = bt[idx*NHEADS + h];
  float b = 14.0f / (1.0f + __expf(-v));
  int clsh = cls >> 1, clsw = cls & 1;
  int ri = (clsh ? HW-WSZ : 0) + i/7, rj = (clsh ? HW-WSZ : 0) + j/7;
  int ci = (clsw ? HW-WSZ : 0) + i%7, cj = (clsw ? HW-WSZ : 0) + j%7;
  int hi = (ri < HW-WSZ) ? 0 : ((ri < HW-SHIFT) ? 1 : 2);
  int hj = (rj < HW-WSZ) ? 0 : ((rj < HW-SHIFT) ? 1 : 2);
  int wi = (ci < HW-WSZ) ? 0 : ((ci < HW-SHIFT) ? 1 : 2);
  int wj = (cj < HW-WSZ) ? 0 : ((cj < HW-SHIFT) ? 1 : 2);
  if ((hi*3 + wi) != (hj*3 + wj)) b -= 100.f;
  cbias[e] = b;
}

// ---------------------------------------------------------------------------
// QKV GEMM: [100352x192] @ [192x576]^T -> qkvg bf16 [tok][q|k|v].
// Channels stored PAIR-INTERLEAVED within each head (pos(d)=d<16?2d:2(d-16)+1)
// so lane l15's two values (cols l15, l15+16) are adjacent -> one dword store
// (48 packed stores/thread, 64B-contiguous per 16-lane group; was 96 scalar
// 2B stores hitting 16x 32B segments/instr). q-k dot is permutation-invariant;
// V/proj compensated by permuted pwb.
// ---------------------------------------------------------------------------
__global__ __launch_bounds__(384) void qkv_kernel(
    const float* __restrict__ x, const ushort_t* __restrict__ qwb,
    const float* __restrict__ qkv_b, ushort_t* __restrict__ qkvg) {
  __shared__ __align__(16) ushort_t s_a[64*AS2];
  int tid = threadIdx.x;
  int lane = tid & 63;
  int h = tid >> 6;                    // wave index == head
  int l15 = lane & 15, quad = lane >> 4;
  size_t tbase = (size_t)blockIdx.x * 64;

  // stage x tile -> bf16 LDS
  for (int e = tid; e < 64*48; e += 384) {
    int t = e / 48, cc = (e % 48) * 4;
    float4 v = *(const float4*)(x + (tbase + t)*CDIM + cc);
    uint_t p0 = (uint_t)f2b(v.x) | ((uint_t)f2b(v.y) << 16);
    uint_t p1 = (uint_t)f2b(v.z) | ((uint_t)f2b(v.w) << 16);
    *(uint_t*)&s_a[t*AS2 + cc]     = p0;
    *(uint_t*)&s_a[t*AS2 + cc + 2] = p1;
  }
  __syncthreads();

  floatx4 acc[6][4];   // [nt][mt]; nt: q0 q1 k0 k1 v0 v1
  #pragma unroll
  for (int nt = 0; nt < 6; ++nt)
    #pragma unroll
    for (int mt = 0; mt < 4; ++mt) acc[nt][mt] = (floatx4){0.f,0.f,0.f,0.f};
  #pragma unroll
  for (int kt = 0; kt < 6; ++kt) {
    short8 a[4];
    #pragma unroll
    for (int mt = 0; mt < 4; ++mt)
      a[mt] = *(const short8*)&s_a[(mt*16 + l15)*AS2 + kt*32 + quad*8];
    #pragma unroll
    for (int nt = 0; nt < 6; ++nt) {
      int o = (nt >> 1)*CDIM + h*HDIM + (nt & 1)*16 + l15;
      short8 b = *(const short8*)&qwb[(size_t)o*CDIM + kt*32 + quad*8];
      #pragma unroll
      for (int mt = 0; mt < 4; ++mt)
        acc[nt][mt] = __builtin_amdgcn_mfma_f32_16x16x32_bf16(a[mt], b, acc[nt][mt], 0, 0, 0);
    }
  }
  // q,k: +bias, cosine-normalize rows, packed dword stores (pair-interleaved)
  #pragma unroll
  for (int w2 = 0; w2 < 2; ++w2) {
    float b0 = qkv_b[w2*CDIM + h*HDIM + l15];
    float b1 = qkv_b[w2*CDIM + h*HDIM + 16 + l15];
    #pragma unroll
    for (int mt = 0; mt < 4; ++mt) {
      float vv[2][4], ss[4];
      #pragma unroll
      for (int r = 0; r < 4; ++r) {
        float t0 = acc[w2*2][mt][r] + b0;
        float t1 = acc[w2*2+1][mt][r] + b1;
        vv[0][r] = t0; vv[1][r] = t1;
        ss[r] = t0*t0 + t1*t1;
      }
      #pragma unroll
      for (int m = 1; m < 16; m <<= 1)
        #pragma unroll
        for (int r = 0; r < 4; ++r) ss[r] += __shfl_xor(ss[r], m, 64);
      #pragma unroll
      for (int r = 0; r < 4; ++r) {
        float inv = 1.0f / fmaxf(sqrtf(ss[r]), 1e-12f);
        size_t tok = tbase + mt*16 + quad*4 + r;
        uint_t pk = (uint_t)f2b(vv[0][r] * inv) | ((uint_t)f2b(vv[1][r] * inv) << 16);
        *(uint_t*)&qkvg[tok*QKS + w2*CDIM + h*HDIM + 2*l15] = pk;
      }
    }
  }
  // v: +bias, packed dword stores (pair-interleaved)
  {
    float b0 = qkv_b[2*CDIM + h*HDIM + l15];
    float b1 = qkv_b[2*CDIM + h*HDIM + 16 + l15];
    #pragma unroll
    for (int mt = 0; mt < 4; ++mt)
      #pragma unroll
      for (int r = 0; r < 4; ++r) {
        size_t tok = tbase + mt*16 + quad*4 + r;
        uint_t pk = (uint_t)f2b(acc[4][mt][r] + b0) | ((uint_t)f2b(acc[5][mt][r] + b1) << 16);
        *(uint_t*)&qkvg[tok*QKS + 2*CDIM + h*HDIM + 2*l15] = pk;
      }
  }
}

// ---------------------------------------------------------------------------
// Slim window attention. 1 window/block (2048), 512 thr = 8 waves (wm,wh).
// q/k frags global->reg; only V^T staged in LDS. Mask folded into cbias.
// All channel indices are in qkvg storage space (pair-interleaved), which is
// self-consistent end-to-end: QK over shared permuted axis, V/proj via
// permuted pwb. s_setprio around MFMA clusters; wave-parallel LN1. 4 barriers.
// ---------------------------------------------------------------------------
__global__ __launch_bounds__(512, 4) void attn_kernel(
    const float* __restrict__ x, const ushort_t* __restrict__ qkvg,
    const ushort_t* __restrict__ pwb, const float* __restrict__ proj_b,
    const float* __restrict__ logit_scale, const float* __restrict__ cbias,
    const float* __restrict__ n1w, const float* __restrict__ n1b,
    float* __restrict__ outp) {
  __shared__ __align__(16) ushort_t sm[192*VTS + 128*PPS + 64*XS];
  ushort_t* s_vt = sm;                 // [192 d][64 tok]
  ushort_t* s_P  = sm + 192*VTS;       // 8 wave slabs x [16][PPS]
  ushort_t* s_o  = s_P + 128*PPS;      // [64][192] attn output
  float*    s_ln = (float*)sm;         // proj fp32 overlay
  __shared__ float s_mu[NTOK], s_rs[NTOK];

  int tid = threadIdx.x;
  int lane = tid & 63;
  int wave = tid >> 6;
  int wm = wave & 3, wh = wave >> 2;
  int l15 = lane & 15, quad = lane >> 4;
  int mrow0 = wm*16 + quad*4;
  int blk = blockIdx.x;
  int bimg = blk >> 6, wh_b = (blk >> 3) & 7, ww_b = blk & 7;
  int rbase = wh_b*WSZ, cbase = ww_b*WSZ;
  const float* cb = cbias +
      (size_t)(((wh_b == 7) ? 2 : 0) + ((ww_b == 7) ? 1 : 0)) * (NHEADS*NTOK*NTOK);

  // per-lane gathered-token row offsets (elements) into qkvg
  int ti_a = wm*16 + l15; ti_a = (ti_a < NTOK) ? ti_a : (NTOK-1);
  int ra = rbase + ti_a/7 + SHIFT; ra -= (ra >= HW) ? HW : 0;
  int ca = cbase + ti_a%7 + SHIFT; ca -= (ca >= HW) ? HW : 0;
  uint_t qrow = (uint_t)((bimg*HW + ra)*HW + ca) * QKS;
  uint_t krow[4];
  #pragma unroll
  for (int nt = 0; nt < 4; ++nt) {
    int tn = nt*16 + l15; tn = (tn < NTOK) ? tn : (NTOK-1);
    int r = rbase + tn/7 + SHIFT; r -= (r >= HW) ? HW : 0;
    int c = cbase + tn%7 + SHIFT; c -= (c >= HW) ? HW : 0;
    krow[nt] = (uint_t)((bimg*HW + r)*HW + c) * QKS + CDIM;
  }
  // hoist q fragments for all 3 of this wave's heads (global -> reg)
  short8 aq[3];
  #pragma unroll
  for (int hh = 0; hh < 3; ++hh)
    aq[hh] = *(const short8*)&qkvg[(size_t)qrow + (wh*3+hh)*HDIM + quad*8];

  // stage V^T (storage-space channel rows)
  for (int e = tid; e < 32*48; e += 512) {
    int tp = e & 31, dg = e >> 5;
    int t0 = 2*tp, t1 = t0 + 1;
    uint2 va = make_uint2(0u, 0u), vb = make_uint2(0u, 0u);
    if (t0 < NTOK) {
      int r = rbase + t0/7 + SHIFT; r -= (r >= HW) ? HW : 0;
      int c = cbase + t0%7 + SHIFT; c -= (c >= HW) ? HW : 0;
      va = *(const uint2*)&qkvg[((size_t)((bimg*HW + r)*HW + c))*QKS + 2*CDIM + dg*4];
    }
    if (t1 < NTOK) {
      int r = rbase + t1/7 + SHIFT; r -= (r >= HW) ? HW : 0;
      int c = cbase + t1%7 + SHIFT; c -= (c >= HW) ? HW : 0;
      vb = *(const uint2*)&qkvg[((size_t)((bimg*HW + r)*HW + c))*QKS + 2*CDIM + dg*4];
    }
    int d = dg*4;
    *(uint_t*)&s_vt[(d  )*VTS + t0] = (va.x & 0xFFFFu) | (vb.x << 16);
    *(uint_t*)&s_vt[(d+1)*VTS + t0] = (va.x >> 16) | (vb.x & 0xFFFF0000u);
    *(uint_t*)&s_vt[(d+2)*VTS + t0] = (va.y & 0xFFFFu) | (vb.y << 16);
    *(uint_t*)&s_vt[(d+3)*VTS + t0] = (va.y >> 16) | (vb.y & 0xFFFF0000u);
  }
  __syncthreads();   // B1: vt visible

  ushort_t* sPh = s_P + wave*16*PPS;   // wave-private P slab
  for (int hh = 0; hh < 3; ++hh) {
    int h = wh*3 + hh;
    short8 bk[4];
    #pragma unroll
    for (int nt = 0; nt < 4; ++nt)
      bk[nt] = *(const short8*)&qkvg[(size_t)krow[nt] + h*HDIM + quad*8];
    floatx4 sv[4];
    __builtin_amdgcn_s_setprio(1);
    #pragma unroll
    for (int nt = 0; nt < 4; ++nt)
      sv[nt] = __builtin_amdgcn_mfma_f32_16x16x32_bf16(aq[hh], bk[nt], (floatx4){0.f,0.f,0.f,0.f}, 0, 0, 0);
    __builtin_amdgcn_s_setprio(0);
    float sc = __expf(fminf(logit_scale[h], 4.6051702f));
    #pragma unroll
    for (int r = 0; r < 4; ++r) {
      int m_tok = mrow0 + r;
      int mi = (m_tok < NTOK) ? m_tok : (NTOK-1);
      float srow[4];
      float mx = -1e30f;
      #pragma unroll
      for (int nt = 0; nt < 4; ++nt) {
        int n = nt*16 + l15;
        int ni = (n < NTOK) ? n : (NTOK-1);
        float s = sv[nt][r]*sc + cb[(h*NTOK + mi)*NTOK + ni];
        if (n >= NTOK) s = -1e30f;
        srow[nt] = s;
        mx = fmaxf(mx, s);
      }
      #pragma unroll
      for (int m = 1; m < 16; m <<= 1) mx = fmaxf(mx, __shfl_xor(mx, m, 64));
      float p[4], sum = 0.f;
      #pragma unroll
      for (int nt = 0; nt < 4; ++nt) { p[nt] = __expf(srow[nt] - mx); sum += p[nt]; }
      #pragma unroll
      for (int m = 1; m < 16; m <<= 1) sum += __shfl_xor(sum, m, 64);
      float inv = 1.0f / sum;
      #pragma unroll
      for (int nt = 0; nt < 4; ++nt) {
        int n = nt*16 + l15;
        sPh[(quad*4 + r)*PPS + n] = (n < NTOK) ? f2b(p[nt]*inv) : (ushort_t)0;
      }
    }
    floatx4 ov[2];
    ov[0] = (floatx4){0.f,0.f,0.f,0.f}; ov[1] = (floatx4){0.f,0.f,0.f,0.f};
    __builtin_amdgcn_s_setprio(1);
    #pragma unroll
    for (int kt = 0; kt < 2; ++kt) {
      short8 ap = *(const short8*)&sPh[l15*PPS + kt*32 + quad*8];
      #pragma unroll
      for (int dt = 0; dt < 2; ++dt) {
        short8 bv = *(const short8*)&s_vt[(h*HDIM + dt*16 + l15)*VTS + kt*32 + quad*8];
        ov[dt] = __builtin_amdgcn_mfma_f32_16x16x32_bf16(ap, bv, ov[dt], 0, 0, 0);
      }
    }
    __builtin_amdgcn_s_setprio(0);
    #pragma unroll
    for (int dt = 0; dt < 2; ++dt)
      #pragma unroll
      for (int r = 0; r < 4; ++r)
        s_o[(mrow0 + r)*XS + h*HDIM + dt*16 + l15] = f2b(ov[dt][r]);
  }
  __syncthreads();   // B2

  // ---- proj GEMM (pwb pre-permuted to storage space) ----
  short8 aof[6];
  #pragma unroll
  for (int kt = 0; kt < 6; ++kt)
    aof[kt] = *(const short8*)&s_o[(wm*16 + l15)*XS + kt*32 + quad*8];
  floatx4 pacc[6];
  #pragma unroll
  for (int j = 0; j < 6; ++j) pacc[j] = (floatx4){0.f,0.f,0.f,0.f};
  #pragma unroll
  for (int kt = 0; kt < 6; ++kt) {
    #pragma unroll
    for (int j = 0; j < 6; ++j) {
      int n = wh*96 + j*16 + l15;
      short8 b = *(const short8*)&pwb[(size_t)n*CDIM + kt*32 + quad*8];
      pacc[j] = __builtin_amdgcn_mfma_f32_16x16x32_bf16(aof[kt], b, pacc[j], 0, 0, 0);
    }
  }
  #pragma unroll
  for (int j = 0; j < 6; ++j) {
    int c = wh*96 + j*16 + l15;
    float pb = proj_b[c];
    #pragma unroll
    for (int r = 0; r < 4; ++r) {
      int m = mrow0 + r;
      if (m < NTOK) s_ln[m*LS + c] = pacc[j][r] + pb;
    }
  }
  __syncthreads();   // B3
  // LN1 stats, wave-parallel: 4 threads/row, shfl-xor reduce over the 4-group
  if (tid < 4*NTOK) {
    int row = tid >> 2, part = tid & 3;
    const float4* rp = (const float4*)(s_ln + row*LS) + part*12;
    float mu = 0.f;
    #pragma unroll
    for (int c = 0; c < 12; ++c) { float4 v = rp[c]; mu += v.x+v.y+v.z+v.w; }
    mu += __shfl_xor(mu, 1, 64);
    mu += __shfl_xor(mu, 2, 64);
    mu *= (1.0f/CDIM);
    float var = 0.f;
    #pragma unroll
    for (int c = 0; c < 12; ++c) {
      float4 v = rp[c];
      float a0=v.x-mu, a1=v.y-mu, a2=v.z-mu, a3=v.w-mu;
      var += a0*a0 + a1*a1 + a2*a2 + a3*a3;
    }
    var += __shfl_xor(var, 1, 64);
    var += __shfl_xor(var, 2, 64);
    var *= (1.0f/CDIM);
    if (part == 0) { s_mu[row] = mu; s_rs[row] = rsqrtf(var + 1e-5f); }
  }
  __syncthreads();   // B4
  for (int e = tid; e < NTOK*48; e += 512) {
    int ti = e / 48, cc = (e % 48) * 4;
    int r = (rbase + ti/WSZ + SHIFT) % HW;
    int cl = (cbase + ti%WSZ + SHIFT) % HW;
    size_t g = (((size_t)bimg*HW + r)*HW + cl)*CDIM + cc;
    float4 xv = *(const float4*)(x + g);
    float4 wv = *(const float4*)(n1w + cc);
    float4 bv = *(const float4*)(n1b + cc);
    float mu = s_mu[ti], rs = s_rs[ti];
    float4 o;
    o.x = xv.x + (s_ln[ti*LS+cc  ] - mu)*rs*wv.x + bv.x;
    o.y = xv.y + (s_ln[ti*LS+cc+1] - mu)*rs*wv.y + bv.y;
    o.z = xv.z + (s_ln[ti*LS+cc+2] - mu)*rs*wv.z + bv.z;
    o.w = xv.w + (s_ln[ti*LS+cc+3] - mu)*rs*wv.w + bv.w;
    *(float4*)(outp + g) = o;
  }
}

// ---------------------------------------------------------------------------
// FALLBACK fused attention if workspace too small for qkvg. V stored at
// pair-interleaved channel rows (d = wh*HDIM + 2*l15 + dt) for consistency
// with the permuted pwb; q/k internal layout needs no change.
// ---------------------------------------------------------------------------
__global__ __launch_bounds__(512, 4) void attn_fused(
    const float* __restrict__ x, const ushort_t* __restrict__ qwb,
    const float* __restrict__ qkv_b, const ushort_t* __restrict__ pwb,
    const float* __restrict__ proj_b, const float* __restrict__ logit_scale,
    const float* __restrict__ cbias, const float* __restrict__ n1w,
    const float* __restrict__ n1b, float* __restrict__ outp) {
  __shared__ __align__(16) ushort_t sm[64*XS + 2*64*QPS + 64*VTS + 2*64*PPS];
  ushort_t* s_x  = sm;
  ushort_t* s_qn = s_x  + 64*XS;
  ushort_t* s_kn = s_qn + 64*QPS;
  ushort_t* s_vt = s_kn + 64*QPS;
  ushort_t* s_P  = s_vt + 64*VTS;
  ushort_t* s_o  = s_x;
  float*    s_ln = (float*)sm;
  __shared__ float s_mu[NTOK], s_rs[NTOK];

  int tid = threadIdx.x;
  int lane = tid & 63;
  int wave = tid >> 6;
  int wm = wave & 3, wh = wave >> 2;
  int l15 = lane & 15, quad = lane >> 4;
  int mrow0 = wm*16 + quad*4;
  int blk = blockIdx.x;
  int bimg = blk >> 6, wh_b = (blk >> 3) & 7, ww_b = blk & 7;
  const float* cb = cbias +
      (size_t)(((wh_b == 7) ? 2 : 0) + ((ww_b == 7) ? 1 : 0)) * (NHEADS*NTOK*NTOK);

  for (int e = tid; e < 64*48; e += 512) {
    int i = e / 48, cc = (e % 48) * 4;
    uint_t p0 = 0, p1 = 0;
    if (i < NTOK) {
      int r = (wh_b*WSZ + i/WSZ + SHIFT) % HW;
      int c = (ww_b*WSZ + i%WSZ + SHIFT) % HW;
      float4 v = *(const float4*)(x + (((size_t)bimg*HW + r)*HW + c)*CDIM + cc);
      p0 = (uint_t)f2b(v.x) | ((uint_t)f2b(v.y) << 16);
      p1 = (uint_t)f2b(v.z) | ((uint_t)f2b(v.w) << 16);
    }
    *(uint_t*)&s_x[i*XS + cc]     = p0;
    *(uint_t*)&s_x[i*XS + cc + 2] = p1;
  }
  __syncthreads();

  short8 axf[6];
  #pragma unroll
  for (int kt = 0; kt < 6; ++kt)
    axf[kt] = *(const short8*)&s_x[(wm*16 + l15)*XS + kt*32 + quad*8];

  for (int g = 0; g < 3; ++g) {
    int h = g*2 + wh;
    floatx4 acc[6];
    #pragma unroll
    for (int nt = 0; nt < 6; ++nt) acc[nt] = (floatx4){0.f,0.f,0.f,0.f};
    #pragma unroll
    for (int kt = 0; kt < 6; ++kt) {
      short8 a = axf[kt];
      #pragma unroll
      for (int nt = 0; nt < 6; ++nt) {
        int o = (nt >> 1)*CDIM + h*HDIM + (nt & 1)*16 + l15;
        short8 b = *(const short8*)&qwb[(size_t)o*CDIM + kt*32 + quad*8];
        acc[nt] = __builtin_amdgcn_mfma_f32_16x16x32_bf16(a, b, acc[nt], 0, 0, 0);
      }
    }
    #pragma unroll
    for (int w2 = 0; w2 < 2; ++w2) {
      float vv[2][4], ss[4];
      #pragma unroll
      for (int r = 0; r < 4; ++r) ss[r] = 0.f;
      #pragma unroll
      for (int dt = 0; dt < 2; ++dt) {
        float bias = qkv_b[w2*CDIM + h*HDIM + dt*16 + l15];
        #pragma unroll
        for (int r = 0; r < 4; ++r) {
          float t = acc[w2*2 + dt][r] + bias;
          vv[dt][r] = t; ss[r] += t*t;
        }
      }
      #pragma unroll
      for (int m = 1; m < 16; m <<= 1)
        #pragma unroll
        for (int r = 0; r < 4; ++r) ss[r] += __shfl_xor(ss[r], m, 64);
      ushort_t* dst = w2 ? s_kn : s_qn;
      #pragma unroll
      for (int r = 0; r < 4; ++r) {
        float inv = 1.0f / fmaxf(sqrtf(ss[r]), 1e-12f);
        #pragma unroll
        for (int dt = 0; dt < 2; ++dt)
          dst[(mrow0 + r)*QPS + wh*HDIM + dt*16 + l15] = f2b(vv[dt][r] * inv);
      }
    }
    #pragma unroll
    for (int dt = 0; dt < 2; ++dt) {
      float bias = qkv_b[2*CDIM + h*HDIM + dt*16 + l15];
      int d = wh*HDIM + 2*l15 + dt;     // pair-interleaved (matches pwb perm)
      #pragma unroll
      for (int rp = 0; rp < 2; ++rp) {
        uint_t pk = (uint_t)f2b(acc[4+dt][2*rp] + bias) |
                    ((uint_t)f2b(acc[4+dt][2*rp+1] + bias) << 16);
        *(uint_t*)&s_vt[d*VTS + mrow0 + 2*rp] = pk;
      }
    }
    __syncthreads();

    short8 aq = *(const short8*)&s_qn[(wm*16 + l15)*QPS + wh*HDIM + quad*8];
    floatx4 sv[4];
    #pragma unroll
    for (int nt = 0; nt < 4; ++nt) {
      short8 bk = *(const short8*)&s_kn[(nt*16 + l15)*QPS + wh*HDIM + quad*8];
      sv[nt] = __builtin_amdgcn_mfma_f32_16x16x32_bf16(aq, bk, (floatx4){0.f,0.f,0.f,0.f}, 0, 0, 0);
    }
    float sc = __expf(fminf(logit_scale[h], 4.6051702f));
    ushort_t* sPh = s_P + wh*64*PPS;
    #pragma unroll
    for (int r = 0; r < 4; ++r) {
      int m_tok = mrow0 + r;
      int mi = (m_tok < NTOK) ? m_tok : (NTOK-1);
      float srow[4];
      float mx = -1e30f;
      #pragma unroll
      for (int nt = 0; nt < 4; ++nt) {
        int n = nt*16 + l15;
        int ni = (n < NTOK) ? n : (NTOK-1);
        float s = sv[nt][r]*sc + cb[(h*NTOK + mi)*NTOK + ni];
        if (n >= NTOK) s = -1e30f;
        srow[nt] = s;
        mx = fmaxf(mx, s);
      }
      #pragma unroll
      for (int m = 1; m < 16; m <<= 1) mx = fmaxf(mx, __shfl_xor(mx, m, 64));
      float p[4], sum = 0.f;
      #pragma unroll
      for (int nt = 0; nt < 4; ++nt) { p[nt] = __expf(srow[nt] - mx); sum += p[nt]; }
      #pragma unroll
      for (int m = 1; m < 16; m <<= 1) sum += __shfl_xor(sum, m, 64);
      float inv = 1.0f / sum;
      #pragma unroll
      for (int nt = 0; nt < 4; ++nt) {
        int n = nt*16 + l15;
        sPh[(mrow0 + r)*PPS + n] = (n < NTOK) ? f2b(p[nt]*inv) : (ushort_t)0;
      }
    }
    floatx4 ov[2];
    ov[0] = (floatx4){0.f,0.f,0.f,0.f}; ov[1] = (floatx4){0.f,0.f,0.f,0.f};
    #pragma unroll
    for (int kt = 0; kt < 2; ++kt) {
      short8 ap = *(const short8*)&sPh[(wm*16 + l15)*PPS + kt*32 + quad*8];
      #pragma unroll
      for (int dt = 0; dt < 2; ++dt) {
        short8 bv = *(const short8*)&s_vt[(wh*HDIM + dt*16 + l15)*VTS + kt*32 + quad*8];
        ov[dt] = __builtin_amdgcn_mfma_f32_16x16x32_bf16(ap, bv, ov[dt], 0, 0, 0);
      }
    }
    #pragma unroll
    for (int dt = 0; dt < 2; ++dt)
      #pragma unroll
      for (int r = 0; r < 4; ++r)
        s_o[(mrow0 + r)*XS + h*HDIM + dt*16 + l15] = f2b(ov[dt][r]);
    __syncthreads();
  }

  short8 aof[6];
  #pragma unroll
  for (int kt = 0; kt < 6; ++kt)
    aof[kt] = *(const short8*)&s_o[(wm*16 + l15)*XS + kt*32 + quad*8];
  __syncthreads();
  floatx4 pacc[6];
  #pragma unroll
  for (int j = 0; j < 6; ++j) pacc[j] = (floatx4){0.f,0.f,0.f,0.f};
  #pragma unroll
  for (int kt = 0; kt < 6; ++kt) {
    #pragma unroll
    for (int j = 0; j < 6; ++j) {
      int n = wh*96 + j*16 + l15;
      short8 b = *(const short8*)&pwb[(size_t)n*CDIM + kt*32 + quad*8];
      pacc[j] = __builtin_amdgcn_mfma_f32_16x16x32_bf16(aof[kt], b, pacc[j], 0, 0, 0);
    }
  }
  #pragma unroll
  for (int j = 0; j < 6; ++j) {
    int c = wh*96 + j*16 + l15;
    float pb = proj_b[c];
    #pragma unroll
    for (int r = 0; r < 4; ++r) {
      int m = mrow0 + r;
      if (m < NTOK) s_ln[m*LS + c] = pacc[j][r] + pb;
    }
  }
  __syncthreads();
  if (tid < NTOK) {
    const float4* row = (const float4*)(s_ln + tid*LS);
    float mu = 0.f;
    #pragma unroll 8
    for (int c = 0; c < 48; ++c) { float4 v = row[c]; mu += v.x+v.y+v.z+v.w; }
    mu *= (1.0f/CDIM);
    float var = 0.f;
    #pragma unroll 8
    for (int c = 0; c < 48; ++c) {
      float4 v = row[c];
      float a0=v.x-mu, a1=v.y-mu, a2=v.z-mu, a3=v.w-mu;
      var += a0*a0 + a1*a1 + a2*a2 + a3*a3;
    }
    var *= (1.0f/CDIM);
    s_mu[tid] = mu; s_rs[tid] = rsqrtf(var + 1e-5f);
  }
  __syncthreads();
  for (int e = tid; e < NTOK*48; e += 512) {
    int ti = e / 48, cc = (e % 48) * 4;
    int r = (wh_b*WSZ + ti/WSZ + SHIFT) % HW;
    int cl = (ww_b*WSZ + ti%WSZ + SHIFT) % HW;
    size_t g = (((size_t)bimg*HW + r)*HW + cl)*CDIM + cc;
    float4 xv = *(const float4*)(x + g);
    float4 wv = *(const float4*)(n1w + cc);
    float4 bv = *(const float4*)(n1b + cc);
    float mu = s_mu[ti], rs = s_rs[ti];
    float4 o;
    o.x = xv.x + (s_ln[ti*LS+cc  ] - mu)*rs*wv.x + bv.x;
    o.y = xv.y + (s_ln[ti*LS+cc+1] - mu)*rs*wv.y + bv.y;
    o.z = xv.z + (s_ln[ti*LS+cc+2] - mu)*rs*wv.z + bv.z;
    o.w = xv.w + (s_ln[ti*LS+cc+3] - mu)*rs*wv.w + bv.w;
    *(float4*)(outp + g) = o;
  }
}

// ---------------------------------------------------------------------------
// Fused MLP (round-9 proven: 4-chunk + double-buffered s_h + gelu_fast +
// f2b cast + wave-parallel LN2). 7 barriers. LDS 76.8 KB. In-place on io.
// ---------------------------------------------------------------------------
__global__ __launch_bounds__(256) void mlp_kernel(
    const ushort_t* __restrict__ w1b, const ushort_t* __restrict__ w2b,
    const float* __restrict__ fc1_b, const float* __restrict__ fc2_b,
    const float* __restrict__ n2w, const float* __restrict__ n2b,
    float* __restrict__ io) {
  __shared__ __align__(16) ushort_t sm2[64*AS2 + 2*64*HS2];
  ushort_t* s_a  = sm2;
  ushort_t* s_h0 = sm2 + 64*AS2;
  ushort_t* s_h1 = s_h0 + 64*HS2;
  float*    s_o  = (float*)sm2;        // [64][OS2] fp32 = 50176 B overlay
  __shared__ float s_mu[64], s_rs[64];

  int tid = threadIdx.x;
  int lane = tid & 63;
  int wave = tid >> 6;
  int l15 = lane & 15, quad = lane >> 4;
  size_t base = (size_t)blockIdx.x * (64*CDIM);

  for (int e = tid; e < 64*48; e += 256) {
    int t = e / 48, cc = (e % 48) * 4;
    float4 v = *(const float4*)(io + base + t*CDIM + cc);
    uint_t p0 = (uint_t)f2b(v.x) | ((uint_t)f2b(v.y) << 16);
    uint_t p1 = (uint_t)f2b(v.z) | ((uint_t)f2b(v.w) << 16);
    *(uint_t*)&s_a[t*AS2 + cc]     = p0;
    *(uint_t*)&s_a[t*AS2 + cc + 2] = p1;
  }
  __syncthreads();   // B0: x1 staged

  floatx4 oacc[12];
  #pragma unroll
  for (int t = 0; t < 12; ++t) oacc[t] = (floatx4){0.f,0.f,0.f,0.f};

  #pragma unroll
  for (int ch = 0; ch < 4; ++ch) {
    ushort_t* sh = (ch & 1) ? s_h1 : s_h0;
    floatx4 hacc[12];
    #pragma unroll
    for (int t = 0; t < 12; ++t) hacc[t] = (floatx4){0.f,0.f,0.f,0.f};
    #pragma unroll
    for (int kt = 0; kt < 6; ++kt) {
      short8 a[4];
      #pragma unroll
      for (int mt = 0; mt < 4; ++mt)
        a[mt] = *(const short8*)&s_a[(mt*16 + l15)*AS2 + kt*32 + quad*8];
      #pragma unroll
      for (int nt = 0; nt < 3; ++nt) {
        int n = ch*192 + wave*48 + nt*16 + l15;
        short8 b = *(const short8*)&w1b[(size_t)n*CDIM + kt*32 + quad*8];
        #pragma unroll
        for (int mt = 0; mt < 4; ++mt)
          hacc[nt*4+mt] = __builtin_amdgcn_mfma_f32_16x16x32_bf16(a[mt], b, hacc[nt*4+mt], 0, 0, 0);
      }
    }
    #pragma unroll
    for (int nt = 0; nt < 3; ++nt) {
      int n = ch*192 + wave*48 + nt*16 + l15;
      int cloc = wave*48 + nt*16 + l15;
      float bias = fc1_b[n];
      #pragma unroll
      for (int mt = 0; mt < 4; ++mt) {
        #pragma unroll
        for (int r = 0; r < 4; ++r) {
          float v = hacc[nt*4+mt][r] + bias;
          sh[(mt*16 + quad*4 + r)*HS2 + cloc] = f2b(gelu_fast(v));
        }
      }
    }
    __syncthreads();   // B(ch): H chunk visible; prev readers of this buf done
    #pragma unroll
    for (int kt = 0; kt < 6; ++kt) {
      short8 a2[4];
      #pragma unroll
      for (int mt = 0; mt < 4; ++mt)
        a2[mt] = *(const short8*)&sh[(mt*16 + l15)*HS2 + kt*32 + quad*8];
      #pragma unroll
      for (int nt = 0; nt < 3; ++nt) {
        int n2 = wave*48 + nt*16 + l15;
        short8 b2 = *(const short8*)&w2b[(size_t)n2*MLPH + ch*192 + kt*32 + quad*8];
        #pragma unroll
        for (int mt = 0; mt < 4; ++mt)
          oacc[nt*4+mt] = __builtin_amdgcn_mfma_f32_16x16x32_bf16(a2[mt], b2, oacc[nt*4+mt], 0, 0, 0);
      }
    }
    // no second barrier: next chunk writes the OTHER buffer
  }

  // O + fc2_b -> s_o (overlay spans s_a+s_h0; in-flight GEMM2(3) reads s_h1)
  #pragma unroll
  for (int nt = 0; nt < 3; ++nt) {
    int c = wave*48 + nt*16 + l15;
    float bb = fc2_b[c];
    #pragma unroll
    for (int mt = 0; mt < 4; ++mt) {
      #pragma unroll
      for (int r = 0; r < 4; ++r)
        s_o[(mt*16 + quad*4 + r)*OS2 + c] = oacc[nt*4+mt][r] + bb;
    }
  }
  __syncthreads();   // B5: s_o complete
  // LN2 stats, wave-parallel: 4 threads/row (64 rows x 4 = 256 threads)
  {
    int row = tid >> 2, part = tid & 3;
    const float4* rp = (const float4*)(s_o + row*OS2) + part*12;
    float mu = 0.f;
    #pragma unroll
    for (int c = 0; c < 12; ++c) { float4 v = rp[c]; mu += v.x+v.y+v.z+v.w; }
    mu += __shfl_xor(mu, 1, 64);
    mu += __shfl_xor(mu, 2, 64);
    mu *= (1.0f/CDIM);
    float var = 0.f;
    #pragma unroll
    for (int c = 0; c < 12; ++c) {
      float4 v = rp[c];
      float a0=v.x-mu, a1=v.y-mu, a2=v.z-mu, a3=v.w-mu;
      var += a0*a0 + a1*a1 + a2*a2 + a3*a3;
    }
    var += __shfl_xor(var, 1, 64);
    var += __shfl_xor(var, 2, 64);
    var *= (1.0f/CDIM);
    if (part == 0) { s_mu[row] = mu; s_rs[row] = rsqrtf(var + 1e-5f); }
  }
  __syncthreads();   // B6
  for (int e = tid; e < 64*48; e += 256) {
    int t = e / 48, cc = (e % 48) * 4;
    float4 xv = *(const float4*)(io + base + t*CDIM + cc);
    float4 wv = *(const float4*)(n2w + cc);
    float4 bv = *(const float4*)(n2b + cc);
    float mu = s_mu[t], rs = s_rs[t];
    float4 o;
    o.x = xv.x + (s_o[t*OS2+cc  ] - mu)*rs*wv.x + bv.x;
    o.y = xv.y + (s_o[t*OS2+cc+1] - mu)*rs*wv.y + bv.y;
    o.z = xv.z + (s_o[t*OS2+cc+2] - mu)*rs*wv.z + bv.z;
    o.w = xv.w + (s_o[t*OS2+cc+3] - mu)*rs*wv.w + bv.w;
    *(float4*)(io + base + t*CDIM + cc) = o;
  }
}

extern "C" void kernel_launch(void* const* d_in, const int* in_sizes, int n_in,
                              void* d_out, int out_size, void* d_ws, size_t ws_size,
                              hipStream_t stream) {
  const float* x           = (const float*)d_in[0];
  const float* qkv_w       = (const float*)d_in[1];
  const float* qkv_b       = (const float*)d_in[2];
  const float* proj_w      = (const float*)d_in[3];
  const float* proj_b      = (const float*)d_in[4];
  const float* logit_scale = (const float*)d_in[5];
  const float* cpb_w1      = (const float*)d_in[6];
  const float* cpb_b1      = (const float*)d_in[7];
  const float* cpb_w2      = (const float*)d_in[8];
  const float* n1w         = (const float*)d_in[9];
  const float* n1b         = (const float*)d_in[10];
  const float* n2w         = (const float*)d_in[11];
  const float* n2b         = (const float*)d_in[12];
  const float* fc1_w       = (const float*)d_in[13];
  const float* fc1_b       = (const float*)d_in[14];
  const float* fc2_w       = (const float*)d_in[15];
  const float* fc2_b       = (const float*)d_in[16];
  float* out = (float*)d_out;

  // workspace layout
  ushort_t* w1b = (ushort_t*)d_ws;            // MLPH*CDIM
  ushort_t* w2b = w1b + MLPH*CDIM;            // CDIM*MLPH
  ushort_t* qwb = w2b + CDIM*MLPH;            // 3*CDIM*CDIM
  ushort_t* pwb = qwb + 3*CDIM*CDIM;          // CDIM*CDIM (col-permuted)
  float* cbias  = (float*)(pwb + CDIM*CDIM);  // 4*6*49*49
  float* bt     = cbias + 4*NHEADS*NTOK*NTOK; // 169*6
  ushort_t* qkvg = (ushort_t*)(bt + 169*NHEADS);  // NTOKENS*576 bf16

  size_t base_b = (size_t)(2*MLPH*CDIM + 4*CDIM*CDIM)*2
                + (size_t)(4*NHEADS*NTOK*NTOK)*4 + (size_t)(169*NHEADS)*4;
  size_t qkvg_b = (size_t)NTOKENS*QKS*2;
  bool split_qkv = ws_size >= base_b + qkvg_b;

  int prep_elems = 2*MLPH*CDIM + 4*CDIM*CDIM;
  hipLaunchKernelGGL(prep_kernel, dim3((prep_elems + 255)/256), dim3(256), 0, stream,
                     fc1_w, fc2_w, qkv_w, proj_w, w1b, w2b, qwb, pwb);
  hipLaunchKernelGGL(cpb1_kernel, dim3((169 + 3)/4), dim3(256), 0, stream,
                     cpb_w1, cpb_b1, cpb_w2, bt);
  hipLaunchKernelGGL(cpb2_kernel, dim3((4*NHEADS*NTOK*NTOK + 255)/256), dim3(256), 0, stream,
                     bt, cbias);
  if (split_qkv) {
    hipLaunchKernelGGL(qkv_kernel, dim3(NTOKENS/64), dim3(384), 0, stream,
                       x, qwb, qkv_b, qkvg);
    hipLaunchKernelGGL(attn_kernel, dim3(2048), dim3(512), 0, stream,
                       x, qkvg, pwb, proj_b, logit_scale, cbias, n1w, n1b, out);
  } else {
    hipLaunchKernelGGL(attn_fused, dim3(2048), dim3(512), 0, stream,
                       x, qwb, qkv_b, pwb, proj_b, logit_scale, cbias, n1w, n1b, out);
  }
  hipLaunchKernelGGL(mlp_kernel, dim3(NTOKENS/64), dim3(256), 0, stream,
                     w1b, w2b, fc1_b, fc2_b, n2w, n2b, out);
}

// Round 11
// 582.702 us; speedup vs baseline: 1.1102x; 1.1102x over previous
//
#include <hip/hip_runtime.h>
#include <math.h>

#define CDIM 192
#define NHEADS 6
#define HDIM 32
#define WSZ 7
#define NTOK 49
#define SHIFT 3
#define HW 56
#define MLPH 768
#define NTOKENS 100352   // 32*56*56
#define QKS 576          // qkvg row stride (q|k|v each 192)
// attn kernel strides (bf16 elems unless noted)
#define XS 200   // s_o row stride
#define VTS 72   // s_vt row stride (192 rows)
#define PPS 72   // s_P row stride (8 wave slabs x 16 rows)
#define LS 196   // s_ln row stride (fp32)
// fused-fallback strides
#define QPS 72
// mlp kernel strides
#define AS2 200  // s_a row stride (bf16)
#define HS2 200  // s_h chunk row stride (bf16, 192 cols)
#define OS2 196  // s_o row stride (fp32)

typedef __attribute__((ext_vector_type(8))) short short8;
typedef __attribute__((ext_vector_type(4))) float floatx4;
typedef unsigned short ushort_t;
typedef unsigned int uint_t;

// float -> bf16 RNE via native cast: clang emits hardware cvt (pairs fuse to
// v_cvt_pk_bf16_f32).
__device__ __forceinline__ ushort_t f2b(float f) {
  __bf16 b = (__bf16)f;
  return __builtin_bit_cast(ushort_t, b);
}

// gelu tanh-form: max dev from exact-erf gelu ~3e-4, below bf16 rounding.
__device__ __forceinline__ float gelu_fast(float v) {
  float u2 = 1.5957691f * v * (1.0f + 0.044715f * v * v);
  float s = 1.0f / (1.0f + __expf(-u2));
  return v * s;
}

// ---------------------------------------------------------------------------
// Prep: convert fc1_w, fc2_w, qkv_w, proj_w to bf16 in workspace.
// pwb columns are PERMUTED within each 32-wide head block to match qkvg's
// pair-interleaved channel layout (pos(d) = d<16 ? 2d : 2(d-16)+1): proj's
// K-axis dot product is invariant under a shared permutation.
// ---------------------------------------------------------------------------
__global__ void prep_kernel(const float* __restrict__ fc1_w, const float* __restrict__ fc2_w,
                            const float* __restrict__ qkv_w, const float* __restrict__ proj_w,
                            ushort_t* __restrict__ w1b, ushort_t* __restrict__ w2b,
                            ushort_t* __restrict__ qwb, ushort_t* __restrict__ pwb) {
  int i = blockIdx.x * 256 + threadIdx.x;
  if (i < MLPH*CDIM) w1b[i] = f2b(fc1_w[i]);
  else if (i < 2*MLPH*CDIM) w2b[i - MLPH*CDIM] = f2b(fc2_w[i - MLPH*CDIM]);
  else if (i < 2*MLPH*CDIM + 3*CDIM*CDIM) qwb[i - 2*MLPH*CDIM] = f2b(qkv_w[i - 2*MLPH*CDIM]);
  else if (i < 2*MLPH*CDIM + 4*CDIM*CDIM) {
    int j = i - 2*MLPH*CDIM - 3*CDIM*CDIM;
    int n = j / CDIM, k = j % CDIM;
    int h = k / 32, kloc = k % 32;
    int pos = (kloc < 16) ? 2*kloc : 2*(kloc-16) + 1;
    pwb[n*CDIM + h*32 + pos] = f2b(proj_w[j]);
  }
}

// ---------------------------------------------------------------------------
// CPB MLP stage 1: bias table (169 x 6). One wave per table entry.
// ---------------------------------------------------------------------------
__global__ __launch_bounds__(256) void cpb1_kernel(const float* __restrict__ w1,
                                                   const float* __restrict__ b1,
                                                   const float* __restrict__ w2,
                                                   float* __restrict__ bt) {
  int wave = threadIdx.x >> 6, lane = threadIdx.x & 63;
  int e = blockIdx.x * 4 + wave;
  if (e >= 169) return;
  const float inv_log2_7 = 0.35620718710802217f;
  int a = e / 13, b = e % 13;
  float v0 = (float)(a - 6) * (7.0f / 6.0f);
  float v1 = (float)(b - 6) * (7.0f / 6.0f);
  float s0 = (v0 > 0.f) ? 1.f : ((v0 < 0.f) ? -1.f : 0.f);
  float s1 = (v1 > 0.f) ? 1.f : ((v1 < 0.f) ? -1.f : 0.f);
  v0 = s0 * log2f(fabsf(v0) + 1.0f) * inv_log2_7;
  v1 = s1 * log2f(fabsf(v1) + 1.0f) * inv_log2_7;
  float acc[NHEADS];
  #pragma unroll
  for (int h = 0; h < NHEADS; ++h) acc[h] = 0.f;
  #pragma unroll
  for (int j = 0; j < 8; ++j) {
    int k = lane + 64*j;
    float hv = v0 * w1[2*k] + v1 * w1[2*k+1] + b1[k];
    hv = (hv > 0.f) ? hv : 0.01f * hv;
    #pragma unroll
    for (int h = 0; h < NHEADS; ++h) acc[h] += hv * w2[h*512 + k];
  }
  #pragma unroll
  for (int m = 1; m < 64; m <<= 1)
    #pragma unroll
    for (int h = 0; h < NHEADS; ++h) acc[h] += __shfl_xor(acc[h], m, 64);
  if (lane == 0) {
    #pragma unroll
    for (int h = 0; h < NHEADS; ++h) bt[e*NHEADS + h] = acc[h];
  }
}

// CPB stage 2: expand to cbias[4 cls][6][49][49] = 14*sigmoid(bias) - 100*mask.
__global__ void cpb2_kernel(const float* __restrict__ bt, float* __restrict__ cbias) {
  int e = blockIdx.x * 256 + threadIdx.x;
  if (e >= 4*NHEADS*NTOK*NTOK) return;
  int cls = e / (NHEADS*NTOK*NTOK);
  int rem = e % (NHEADS*NTOK*NTOK);
  int h = rem / (NTOK*NTOK);
  int r = rem % (NTOK*NTOK);
  int i = r / NTOK, j = r % NTOK;
  int idx = (i/7 - j/7 + 6) * 13 + (i%7 - j%7 + 6);
  float v = bt[idx*NHEADS + h];
  float b = 14.0f / (1.0f + __expf(-v));
  int clsh = cls >> 1, clsw = cls & 1;
  int ri = (clsh ? HW-WSZ : 0) + i/7, rj = (clsh ? HW-WSZ : 0) + j/7;
  int ci = (clsw ? HW-WSZ : 0) + i%7, cj = (clsw ? HW-WSZ : 0) + j%7;
  int hi = (ri < HW-WSZ) ? 0 : ((ri < HW-SHIFT) ? 1 : 2);
  int hj = (rj < HW-WSZ) ? 0 : ((rj < HW-SHIFT) ? 1 : 2);
  int wi = (ci < HW-WSZ) ? 0 : ((ci < HW-SHIFT) ? 1 : 2);
  int wj = (cj < HW-WSZ) ? 0 : ((cj < HW-SHIFT) ? 1 : 2);
  if ((hi*3 + wi) != (hj*3 + wj)) b -= 100.f;
  cbias[e] = b;
}

// ---------------------------------------------------------------------------
// QKV GEMM: [100352x192] @ [192x576]^T -> qkvg bf16 [tok][q|k|v].
// Channels stored PAIR-INTERLEAVED within each head (pos(d)=d<16?2d:2(d-16)+1)
// so lane l15's two values (cols l15, l15+16) are adjacent -> one dword store
// (48 packed stores/thread, 4x64B wave segments; was 96 scalar 2B stores at
// 16x32B segments/instr). q-k dot is permutation-invariant; V/proj
// compensated by permuted pwb.
// ---------------------------------------------------------------------------
__global__ __launch_bounds__(384) void qkv_kernel(
    const float* __restrict__ x, const ushort_t* __restrict__ qwb,
    const float* __restrict__ qkv_b, ushort_t* __restrict__ qkvg) {
  __shared__ __align__(16) ushort_t s_a[64*AS2];
  int tid = threadIdx.x;
  int lane = tid & 63;
  int h = tid >> 6;                    // wave index == head
  int l15 = lane & 15, quad = lane >> 4;
  size_t tbase = (size_t)blockIdx.x * 64;

  // stage x tile -> bf16 LDS
  for (int e = tid; e < 64*48; e += 384) {
    int t = e / 48, cc = (e % 48) * 4;
    float4 v = *(const float4*)(x + (tbase + t)*CDIM + cc);
    uint_t p0 = (uint_t)f2b(v.x) | ((uint_t)f2b(v.y) << 16);
    uint_t p1 = (uint_t)f2b(v.z) | ((uint_t)f2b(v.w) << 16);
    *(uint_t*)&s_a[t*AS2 + cc]     = p0;
    *(uint_t*)&s_a[t*AS2 + cc + 2] = p1;
  }
  __syncthreads();

  floatx4 acc[6][4];   // [nt][mt]; nt: q0 q1 k0 k1 v0 v1
  #pragma unroll
  for (int nt = 0; nt < 6; ++nt)
    #pragma unroll
    for (int mt = 0; mt < 4; ++mt) acc[nt][mt] = (floatx4){0.f,0.f,0.f,0.f};
  #pragma unroll
  for (int kt = 0; kt < 6; ++kt) {
    short8 a[4];
    #pragma unroll
    for (int mt = 0; mt < 4; ++mt)
      a[mt] = *(const short8*)&s_a[(mt*16 + l15)*AS2 + kt*32 + quad*8];
    #pragma unroll
    for (int nt = 0; nt < 6; ++nt) {
      int o = (nt >> 1)*CDIM + h*HDIM + (nt & 1)*16 + l15;
      short8 b = *(const short8*)&qwb[(size_t)o*CDIM + kt*32 + quad*8];
      #pragma unroll
      for (int mt = 0; mt < 4; ++mt)
        acc[nt][mt] = __builtin_amdgcn_mfma_f32_16x16x32_bf16(a[mt], b, acc[nt][mt], 0, 0, 0);
    }
  }
  // q,k: +bias, cosine-normalize rows, packed dword stores (pair-interleaved)
  #pragma unroll
  for (int w2 = 0; w2 < 2; ++w2) {
    float b0 = qkv_b[w2*CDIM + h*HDIM + l15];
    float b1 = qkv_b[w2*CDIM + h*HDIM + 16 + l15];
    #pragma unroll
    for (int mt = 0; mt < 4; ++mt) {
      float vv[2][4], ss[4];
      #pragma unroll
      for (int r = 0; r < 4; ++r) {
        float t0 = acc[w2*2][mt][r] + b0;
        float t1 = acc[w2*2+1][mt][r] + b1;
        vv[0][r] = t0; vv[1][r] = t1;
        ss[r] = t0*t0 + t1*t1;
      }
      #pragma unroll
      for (int m = 1; m < 16; m <<= 1)
        #pragma unroll
        for (int r = 0; r < 4; ++r) ss[r] += __shfl_xor(ss[r], m, 64);
      #pragma unroll
      for (int r = 0; r < 4; ++r) {
        float inv = 1.0f / fmaxf(sqrtf(ss[r]), 1e-12f);
        size_t tok = tbase + mt*16 + quad*4 + r;
        uint_t pk = (uint_t)f2b(vv[0][r] * inv) | ((uint_t)f2b(vv[1][r] * inv) << 16);
        *(uint_t*)&qkvg[tok*QKS + w2*CDIM + h*HDIM + 2*l15] = pk;
      }
    }
  }
  // v: +bias, packed dword stores (pair-interleaved)
  {
    float b0 = qkv_b[2*CDIM + h*HDIM + l15];
    float b1 = qkv_b[2*CDIM + h*HDIM + 16 + l15];
    #pragma unroll
    for (int mt = 0; mt < 4; ++mt)
      #pragma unroll
      for (int r = 0; r < 4; ++r) {
        size_t tok = tbase + mt*16 + quad*4 + r;
        uint_t pk = (uint_t)f2b(acc[4][mt][r] + b0) | ((uint_t)f2b(acc[5][mt][r] + b1) << 16);
        *(uint_t*)&qkvg[tok*QKS + 2*CDIM + h*HDIM + 2*l15] = pk;
      }
  }
}

// ---------------------------------------------------------------------------
// Slim window attention. 1 window/block (2048), 512 thr = 8 waves (wm,wh).
// q/k frags global->reg; only V^T staged in LDS. Mask folded into cbias.
// All channel indices in qkvg storage space (pair-interleaved, end-to-end
// consistent). setprio around MFMA clusters; wave-parallel LN1; NEW: k-frag
// loads software-pipelined one head ahead (L2 latency hides under softmax+PV).
// 4 barriers.
// ---------------------------------------------------------------------------
__global__ __launch_bounds__(512, 4) void attn_kernel(
    const float* __restrict__ x, const ushort_t* __restrict__ qkvg,
    const ushort_t* __restrict__ pwb, const float* __restrict__ proj_b,
    const float* __restrict__ logit_scale, const float* __restrict__ cbias,
    const float* __restrict__ n1w, const float* __restrict__ n1b,
    float* __restrict__ outp) {
  __shared__ __align__(16) ushort_t sm[192*VTS + 128*PPS + 64*XS];
  ushort_t* s_vt = sm;                 // [192 d][64 tok]
  ushort_t* s_P  = sm + 192*VTS;       // 8 wave slabs x [16][PPS]
  ushort_t* s_o  = s_P + 128*PPS;      // [64][192] attn output
  float*    s_ln = (float*)sm;         // proj fp32 overlay
  __shared__ float s_mu[NTOK], s_rs[NTOK];

  int tid = threadIdx.x;
  int lane = tid & 63;
  int wave = tid >> 6;
  int wm = wave & 3, wh = wave >> 2;
  int l15 = lane & 15, quad = lane >> 4;
  int mrow0 = wm*16 + quad*4;
  int blk = blockIdx.x;
  int bimg = blk >> 6, wh_b = (blk >> 3) & 7, ww_b = blk & 7;
  int rbase = wh_b*WSZ, cbase = ww_b*WSZ;
  const float* cb = cbias +
      (size_t)(((wh_b == 7) ? 2 : 0) + ((ww_b == 7) ? 1 : 0)) * (NHEADS*NTOK*NTOK);

  // per-lane gathered-token row offsets (elements) into qkvg
  int ti_a = wm*16 + l15; ti_a = (ti_a < NTOK) ? ti_a : (NTOK-1);
  int ra = rbase + ti_a/7 + SHIFT; ra -= (ra >= HW) ? HW : 0;
  int ca = cbase + ti_a%7 + SHIFT; ca -= (ca >= HW) ? HW : 0;
  uint_t qrow = (uint_t)((bimg*HW + ra)*HW + ca) * QKS;
  uint_t krow[4];
  #pragma unroll
  for (int nt = 0; nt < 4; ++nt) {
    int tn = nt*16 + l15; tn = (tn < NTOK) ? tn : (NTOK-1);
    int r = rbase + tn/7 + SHIFT; r -= (r >= HW) ? HW : 0;
    int c = cbase + tn%7 + SHIFT; c -= (c >= HW) ? HW : 0;
    krow[nt] = (uint_t)((bimg*HW + r)*HW + c) * QKS + CDIM;
  }
  // hoist q fragments for all 3 of this wave's heads (global -> reg)
  short8 aq[3];
  #pragma unroll
  for (int hh = 0; hh < 3; ++hh)
    aq[hh] = *(const short8*)&qkvg[(size_t)qrow + (wh*3+hh)*HDIM + quad*8];

  // stage V^T (storage-space channel rows)
  for (int e = tid; e < 32*48; e += 512) {
    int tp = e & 31, dg = e >> 5;
    int t0 = 2*tp, t1 = t0 + 1;
    uint2 va = make_uint2(0u, 0u), vb = make_uint2(0u, 0u);
    if (t0 < NTOK) {
      int r = rbase + t0/7 + SHIFT; r -= (r >= HW) ? HW : 0;
      int c = cbase + t0%7 + SHIFT; c -= (c >= HW) ? HW : 0;
      va = *(const uint2*)&qkvg[((size_t)((bimg*HW + r)*HW + c))*QKS + 2*CDIM + dg*4];
    }
    if (t1 < NTOK) {
      int r = rbase + t1/7 + SHIFT; r -= (r >= HW) ? HW : 0;
      int c = cbase + t1%7 + SHIFT; c -= (c >= HW) ? HW : 0;
      vb = *(const uint2*)&qkvg[((size_t)((bimg*HW + r)*HW + c))*QKS + 2*CDIM + dg*4];
    }
    int d = dg*4;
    *(uint_t*)&s_vt[(d  )*VTS + t0] = (va.x & 0xFFFFu) | (vb.x << 16);
    *(uint_t*)&s_vt[(d+1)*VTS + t0] = (va.x >> 16) | (vb.x & 0xFFFF0000u);
    *(uint_t*)&s_vt[(d+2)*VTS + t0] = (va.y & 0xFFFFu) | (vb.y << 16);
    *(uint_t*)&s_vt[(d+3)*VTS + t0] = (va.y >> 16) | (vb.y & 0xFFFF0000u);
  }
  __syncthreads();   // B1: vt visible

  ushort_t* sPh = s_P + wave*16*PPS;   // wave-private P slab
  // k-frag pipeline: preload head 0
  short8 bk[4];
  #pragma unroll
  for (int nt = 0; nt < 4; ++nt)
    bk[nt] = *(const short8*)&qkvg[(size_t)krow[nt] + (wh*3)*HDIM + quad*8];
  for (int hh = 0; hh < 3; ++hh) {
    int h = wh*3 + hh;
    floatx4 sv[4];
    __builtin_amdgcn_s_setprio(1);
    #pragma unroll
    for (int nt = 0; nt < 4; ++nt)
      sv[nt] = __builtin_amdgcn_mfma_f32_16x16x32_bf16(aq[hh], bk[nt], (floatx4){0.f,0.f,0.f,0.f}, 0, 0, 0);
    __builtin_amdgcn_s_setprio(0);
    // prefetch next head's k frags: L2 latency hides under softmax + PV
    if (hh < 2) {
      #pragma unroll
      for (int nt = 0; nt < 4; ++nt)
        bk[nt] = *(const short8*)&qkvg[(size_t)krow[nt] + (h+1)*HDIM + quad*8];
    }
    float sc = __expf(fminf(logit_scale[h], 4.6051702f));
    #pragma unroll
    for (int r = 0; r < 4; ++r) {
      int m_tok = mrow0 + r;
      int mi = (m_tok < NTOK) ? m_tok : (NTOK-1);
      float srow[4];
      float mx = -1e30f;
      #pragma unroll
      for (int nt = 0; nt < 4; ++nt) {
        int n = nt*16 + l15;
        int ni = (n < NTOK) ? n : (NTOK-1);
        float s = sv[nt][r]*sc + cb[(h*NTOK + mi)*NTOK + ni];
        if (n >= NTOK) s = -1e30f;
        srow[nt] = s;
        mx = fmaxf(mx, s);
      }
      #pragma unroll
      for (int m = 1; m < 16; m <<= 1) mx = fmaxf(mx, __shfl_xor(mx, m, 64));
      float p[4], sum = 0.f;
      #pragma unroll
      for (int nt = 0; nt < 4; ++nt) { p[nt] = __expf(srow[nt] - mx); sum += p[nt]; }
      #pragma unroll
      for (int m = 1; m < 16; m <<= 1) sum += __shfl_xor(sum, m, 64);
      float inv = 1.0f / sum;
      #pragma unroll
      for (int nt = 0; nt < 4; ++nt) {
        int n = nt*16 + l15;
        sPh[(quad*4 + r)*PPS + n] = (n < NTOK) ? f2b(p[nt]*inv) : (ushort_t)0;
      }
    }
    floatx4 ov[2];
    ov[0] = (floatx4){0.f,0.f,0.f,0.f}; ov[1] = (floatx4){0.f,0.f,0.f,0.f};
    __builtin_amdgcn_s_setprio(1);
    #pragma unroll
    for (int kt = 0; kt < 2; ++kt) {
      short8 ap = *(const short8*)&sPh[l15*PPS + kt*32 + quad*8];
      #pragma unroll
      for (int dt = 0; dt < 2; ++dt) {
        short8 bv = *(const short8*)&s_vt[(h*HDIM + dt*16 + l15)*VTS + kt*32 + quad*8];
        ov[dt] = __builtin_amdgcn_mfma_f32_16x16x32_bf16(ap, bv, ov[dt], 0, 0, 0);
      }
    }
    __builtin_amdgcn_s_setprio(0);
    #pragma unroll
    for (int dt = 0; dt < 2; ++dt)
      #pragma unroll
      for (int r = 0; r < 4; ++r)
        s_o[(mrow0 + r)*XS + h*HDIM + dt*16 + l15] = f2b(ov[dt][r]);
  }
  __syncthreads();   // B2

  // ---- proj GEMM (pwb pre-permuted to storage space) ----
  short8 aof[6];
  #pragma unroll
  for (int kt = 0; kt < 6; ++kt)
    aof[kt] = *(const short8*)&s_o[(wm*16 + l15)*XS + kt*32 + quad*8];
  floatx4 pacc[6];
  #pragma unroll
  for (int j = 0; j < 6; ++j) pacc[j] = (floatx4){0.f,0.f,0.f,0.f};
  #pragma unroll
  for (int kt = 0; kt < 6; ++kt) {
    #pragma unroll
    for (int j = 0; j < 6; ++j) {
      int n = wh*96 + j*16 + l15;
      short8 b = *(const short8*)&pwb[(size_t)n*CDIM + kt*32 + quad*8];
      pacc[j] = __builtin_amdgcn_mfma_f32_16x16x32_bf16(aof[kt], b, pacc[j], 0, 0, 0);
    }
  }
  #pragma unroll
  for (int j = 0; j < 6; ++j) {
    int c = wh*96 + j*16 + l15;
    float pb = proj_b[c];
    #pragma unroll
    for (int r = 0; r < 4; ++r) {
      int m = mrow0 + r;
      if (m < NTOK) s_ln[m*LS + c] = pacc[j][r] + pb;
    }
  }
  __syncthreads();   // B3
  // LN1 stats, wave-parallel: 4 threads/row, shfl-xor reduce over the 4-group
  if (tid < 4*NTOK) {
    int row = tid >> 2, part = tid & 3;
    const float4* rp = (const float4*)(s_ln + row*LS) + part*12;
    float mu = 0.f;
    #pragma unroll
    for (int c = 0; c < 12; ++c) { float4 v = rp[c]; mu += v.x+v.y+v.z+v.w; }
    mu += __shfl_xor(mu, 1, 64);
    mu += __shfl_xor(mu, 2, 64);
    mu *= (1.0f/CDIM);
    float var = 0.f;
    #pragma unroll
    for (int c = 0; c < 12; ++c) {
      float4 v = rp[c];
      float a0=v.x-mu, a1=v.y-mu, a2=v.z-mu, a3=v.w-mu;
      var += a0*a0 + a1*a1 + a2*a2 + a3*a3;
    }
    var += __shfl_xor(var, 1, 64);
    var += __shfl_xor(var, 2, 64);
    var *= (1.0f/CDIM);
    if (part == 0) { s_mu[row] = mu; s_rs[row] = rsqrtf(var + 1e-5f); }
  }
  __syncthreads();   // B4
  for (int e = tid; e < NTOK*48; e += 512) {
    int ti = e / 48, cc = (e % 48) * 4;
    int r = (rbase + ti/WSZ + SHIFT) % HW;
    int cl = (cbase + ti%WSZ + SHIFT) % HW;
    size_t g = (((size_t)bimg*HW + r)*HW + cl)*CDIM + cc;
    float4 xv = *(const float4*)(x + g);
    float4 wv = *(const float4*)(n1w + cc);
    float4 bv = *(const float4*)(n1b + cc);
    float mu = s_mu[ti], rs = s_rs[ti];
    float4 o;
    o.x = xv.x + (s_ln[ti*LS+cc  ] - mu)*rs*wv.x + bv.x;
    o.y = xv.y + (s_ln[ti*LS+cc+1] - mu)*rs*wv.y + bv.y;
    o.z = xv.z + (s_ln[ti*LS+cc+2] - mu)*rs*wv.z + bv.z;
    o.w = xv.w + (s_ln[ti*LS+cc+3] - mu)*rs*wv.w + bv.w;
    *(float4*)(outp + g) = o;
  }
}

// ---------------------------------------------------------------------------
// FALLBACK fused attention if workspace too small for qkvg. V stored at
// pair-interleaved channel rows (d = wh*HDIM + 2*l15 + dt) for consistency
// with the permuted pwb; q/k internal layout needs no change.
// ---------------------------------------------------------------------------
__global__ __launch_bounds__(512, 4) void attn_fused(
    const float* __restrict__ x, const ushort_t* __restrict__ qwb,
    const float* __restrict__ qkv_b, const ushort_t* __restrict__ pwb,
    const float* __restrict__ proj_b, const float* __restrict__ logit_scale,
    const float* __restrict__ cbias, const float* __restrict__ n1w,
    const float* __restrict__ n1b, float* __restrict__ outp) {
  __shared__ __align__(16) ushort_t sm[64*XS + 2*64*QPS + 64*VTS + 2*64*PPS];
  ushort_t* s_x  = sm;
  ushort_t* s_qn = s_x  + 64*XS;
  ushort_t* s_kn = s_qn + 64*QPS;
  ushort_t* s_vt = s_kn + 64*QPS;
  ushort_t* s_P  = s_vt + 64*VTS;
  ushort_t* s_o  = s_x;
  float*    s_ln = (float*)sm;
  __shared__ float s_mu[NTOK], s_rs[NTOK];

  int tid = threadIdx.x;
  int lane = tid & 63;
  int wave = tid >> 6;
  int wm = wave & 3, wh = wave >> 2;
  int l15 = lane & 15, quad = lane >> 4;
  int mrow0 = wm*16 + quad*4;
  int blk = blockIdx.x;
  int bimg = blk >> 6, wh_b = (blk >> 3) & 7, ww_b = blk & 7;
  const float* cb = cbias +
      (size_t)(((wh_b == 7) ? 2 : 0) + ((ww_b == 7) ? 1 : 0)) * (NHEADS*NTOK*NTOK);

  for (int e = tid; e < 64*48; e += 512) {
    int i = e / 48, cc = (e % 48) * 4;
    uint_t p0 = 0, p1 = 0;
    if (i < NTOK) {
      int r = (wh_b*WSZ + i/WSZ + SHIFT) % HW;
      int c = (ww_b*WSZ + i%WSZ + SHIFT) % HW;
      float4 v = *(const float4*)(x + (((size_t)bimg*HW + r)*HW + c)*CDIM + cc);
      p0 = (uint_t)f2b(v.x) | ((uint_t)f2b(v.y) << 16);
      p1 = (uint_t)f2b(v.z) | ((uint_t)f2b(v.w) << 16);
    }
    *(uint_t*)&s_x[i*XS + cc]     = p0;
    *(uint_t*)&s_x[i*XS + cc + 2] = p1;
  }
  __syncthreads();

  short8 axf[6];
  #pragma unroll
  for (int kt = 0; kt < 6; ++kt)
    axf[kt] = *(const short8*)&s_x[(wm*16 + l15)*XS + kt*32 + quad*8];

  for (int g = 0; g < 3; ++g) {
    int h = g*2 + wh;
    floatx4 acc[6];
    #pragma unroll
    for (int nt = 0; nt < 6; ++nt) acc[nt] = (floatx4){0.f,0.f,0.f,0.f};
    #pragma unroll
    for (int kt = 0; kt < 6; ++kt) {
      short8 a = axf[kt];
      #pragma unroll
      for (int nt = 0; nt < 6; ++nt) {
        int o = (nt >> 1)*CDIM + h*HDIM + (nt & 1)*16 + l15;
        short8 b = *(const short8*)&qwb[(size_t)o*CDIM + kt*32 + quad*8];
        acc[nt] = __builtin_amdgcn_mfma_f32_16x16x32_bf16(a, b, acc[nt], 0, 0, 0);
      }
    }
    #pragma unroll
    for (int w2 = 0; w2 < 2; ++w2) {
      float vv[2][4], ss[4];
      #pragma unroll
      for (int r = 0; r < 4; ++r) ss[r] = 0.f;
      #pragma unroll
      for (int dt = 0; dt < 2; ++dt) {
        float bias = qkv_b[w2*CDIM + h*HDIM + dt*16 + l15];
        #pragma unroll
        for (int r = 0; r < 4; ++r) {
          float t = acc[w2*2 + dt][r] + bias;
          vv[dt][r] = t; ss[r] += t*t;
        }
      }
      #pragma unroll
      for (int m = 1; m < 16; m <<= 1)
        #pragma unroll
        for (int r = 0; r < 4; ++r) ss[r] += __shfl_xor(ss[r], m, 64);
      ushort_t* dst = w2 ? s_kn : s_qn;
      #pragma unroll
      for (int r = 0; r < 4; ++r) {
        float inv = 1.0f / fmaxf(sqrtf(ss[r]), 1e-12f);
        #pragma unroll
        for (int dt = 0; dt < 2; ++dt)
          dst[(mrow0 + r)*QPS + wh*HDIM + dt*16 + l15] = f2b(vv[dt][r] * inv);
      }
    }
    #pragma unroll
    for (int dt = 0; dt < 2; ++dt) {
      float bias = qkv_b[2*CDIM + h*HDIM + dt*16 + l15];
      int d = wh*HDIM + 2*l15 + dt;     // pair-interleaved (matches pwb perm)
      #pragma unroll
      for (int rp = 0; rp < 2; ++rp) {
        uint_t pk = (uint_t)f2b(acc[4+dt][2*rp] + bias) |
                    ((uint_t)f2b(acc[4+dt][2*rp+1] + bias) << 16);
        *(uint_t*)&s_vt[d*VTS + mrow0 + 2*rp] = pk;
      }
    }
    __syncthreads();

    short8 aq = *(const short8*)&s_qn[(wm*16 + l15)*QPS + wh*HDIM + quad*8];
    floatx4 sv[4];
    #pragma unroll
    for (int nt = 0; nt < 4; ++nt) {
      short8 bk = *(const short8*)&s_kn[(nt*16 + l15)*QPS + wh*HDIM + quad*8];
      sv[nt] = __builtin_amdgcn_mfma_f32_16x16x32_bf16(aq, bk, (floatx4){0.f,0.f,0.f,0.f}, 0, 0, 0);
    }
    float sc = __expf(fminf(logit_scale[h], 4.6051702f));
    ushort_t* sPh = s_P + wh*64*PPS;
    #pragma unroll
    for (int r = 0; r < 4; ++r) {
      int m_tok = mrow0 + r;
      int mi = (m_tok < NTOK) ? m_tok : (NTOK-1);
      float srow[4];
      float mx = -1e30f;
      #pragma unroll
      for (int nt = 0; nt < 4; ++nt) {
        int n = nt*16 + l15;
        int ni = (n < NTOK) ? n : (NTOK-1);
        float s = sv[nt][r]*sc + cb[(h*NTOK + mi)*NTOK + ni];
        if (n >= NTOK) s = -1e30f;
        srow[nt] = s;
        mx = fmaxf(mx, s);
      }
      #pragma unroll
      for (int m = 1; m < 16; m <<= 1) mx = fmaxf(mx, __shfl_xor(mx, m, 64));
      float p[4], sum = 0.f;
      #pragma unroll
      for (int nt = 0; nt < 4; ++nt) { p[nt] = __expf(srow[nt] - mx); sum += p[nt]; }
      #pragma unroll
      for (int m = 1; m < 16; m <<= 1) sum += __shfl_xor(sum, m, 64);
      float inv = 1.0f / sum;
      #pragma unroll
      for (int nt = 0; nt < 4; ++nt) {
        int n = nt*16 + l15;
        sPh[(mrow0 + r)*PPS + n] = (n < NTOK) ? f2b(p[nt]*inv) : (ushort_t)0;
      }
    }
    floatx4 ov[2];
    ov[0] = (floatx4){0.f,0.f,0.f,0.f}; ov[1] = (floatx4){0.f,0.f,0.f,0.f};
    #pragma unroll
    for (int kt = 0; kt < 2; ++kt) {
      short8 ap = *(const short8*)&sPh[(wm*16 + l15)*PPS + kt*32 + quad*8];
      #pragma unroll
      for (int dt = 0; dt < 2; ++dt) {
        short8 bv = *(const short8*)&s_vt[(wh*HDIM + dt*16 + l15)*VTS + kt*32 + quad*8];
        ov[dt] = __builtin_amdgcn_mfma_f32_16x16x32_bf16(ap, bv, ov[dt], 0, 0, 0);
      }
    }
    #pragma unroll
    for (int dt = 0; dt < 2; ++dt)
      #pragma unroll
      for (int r = 0; r < 4; ++r)
        s_o[(mrow0 + r)*XS + h*HDIM + dt*16 + l15] = f2b(ov[dt][r]);
    __syncthreads();
  }

  short8 aof[6];
  #pragma unroll
  for (int kt = 0; kt < 6; ++kt)
    aof[kt] = *(const short8*)&s_o[(wm*16 + l15)*XS + kt*32 + quad*8];
  __syncthreads();
  floatx4 pacc[6];
  #pragma unroll
  for (int j = 0; j < 6; ++j) pacc[j] = (floatx4){0.f,0.f,0.f,0.f};
  #pragma unroll
  for (int kt = 0; kt < 6; ++kt) {
    #pragma unroll
    for (int j = 0; j < 6; ++j) {
      int n = wh*96 + j*16 + l15;
      short8 b = *(const short8*)&pwb[(size_t)n*CDIM + kt*32 + quad*8];
      pacc[j] = __builtin_amdgcn_mfma_f32_16x16x32_bf16(aof[kt], b, pacc[j], 0, 0, 0);
    }
  }
  #pragma unroll
  for (int j = 0; j < 6; ++j) {
    int c = wh*96 + j*16 + l15;
    float pb = proj_b[c];
    #pragma unroll
    for (int r = 0; r < 4; ++r) {
      int m = mrow0 + r;
      if (m < NTOK) s_ln[m*LS + c] = pacc[j][r] + pb;
    }
  }
  __syncthreads();
  if (tid < NTOK) {
    const float4* row = (const float4*)(s_ln + tid*LS);
    float mu = 0.f;
    #pragma unroll 8
    for (int c = 0; c < 48; ++c) { float4 v = row[c]; mu += v.x+v.y+v.z+v.w; }
    mu *= (1.0f/CDIM);
    float var = 0.f;
    #pragma unroll 8
    for (int c = 0; c < 48; ++c) {
      float4 v = row[c];
      float a0=v.x-mu, a1=v.y-mu, a2=v.z-mu, a3=v.w-mu;
      var += a0*a0 + a1*a1 + a2*a2 + a3*a3;
    }
    var *= (1.0f/CDIM);
    s_mu[tid] = mu; s_rs[tid] = rsqrtf(var + 1e-5f);
  }
  __syncthreads();
  for (int e = tid; e < NTOK*48; e += 512) {
    int ti = e / 48, cc = (e % 48) * 4;
    int r = (wh_b*WSZ + ti/WSZ + SHIFT) % HW;
    int cl = (ww_b*WSZ + ti%WSZ + SHIFT) % HW;
    size_t g = (((size_t)bimg*HW + r)*HW + cl)*CDIM + cc;
    float4 xv = *(const float4*)(x + g);
    float4 wv = *(const float4*)(n1w + cc);
    float4 bv = *(const float4*)(n1b + cc);
    float mu = s_mu[ti], rs = s_rs[ti];
    float4 o;
    o.x = xv.x + (s_ln[ti*LS+cc  ] - mu)*rs*wv.x + bv.x;
    o.y = xv.y + (s_ln[ti*LS+cc+1] - mu)*rs*wv.y + bv.y;
    o.z = xv.z + (s_ln[ti*LS+cc+2] - mu)*rs*wv.z + bv.z;
    o.w = xv.w + (s_ln[ti*LS+cc+3] - mu)*rs*wv.w + bv.w;
    *(float4*)(outp + g) = o;
  }
}

// ---------------------------------------------------------------------------
// Fused MLP (round-9 proven: 4-chunk + double-buffered s_h + gelu_fast +
// f2b cast + wave-parallel LN2). 7 barriers. LDS 76.8 KB. In-place on io.
// ---------------------------------------------------------------------------
__global__ __launch_bounds__(256) void mlp_kernel(
    const ushort_t* __restrict__ w1b, const ushort_t* __restrict__ w2b,
    const float* __restrict__ fc1_b, const float* __restrict__ fc2_b,
    const float* __restrict__ n2w, const float* __restrict__ n2b,
    float* __restrict__ io) {
  __shared__ __align__(16) ushort_t sm2[64*AS2 + 2*64*HS2];
  ushort_t* s_a  = sm2;
  ushort_t* s_h0 = sm2 + 64*AS2;
  ushort_t* s_h1 = s_h0 + 64*HS2;
  float*    s_o  = (float*)sm2;        // [64][OS2] fp32 = 50176 B overlay
  __shared__ float s_mu[64], s_rs[64];

  int tid = threadIdx.x;
  int lane = tid & 63;
  int wave = tid >> 6;
  int l15 = lane & 15, quad = lane >> 4;
  size_t base = (size_t)blockIdx.x * (64*CDIM);

  for (int e = tid; e < 64*48; e += 256) {
    int t = e / 48, cc = (e % 48) * 4;
    float4 v = *(const float4*)(io + base + t*CDIM + cc);
    uint_t p0 = (uint_t)f2b(v.x) | ((uint_t)f2b(v.y) << 16);
    uint_t p1 = (uint_t)f2b(v.z) | ((uint_t)f2b(v.w) << 16);
    *(uint_t*)&s_a[t*AS2 + cc]     = p0;
    *(uint_t*)&s_a[t*AS2 + cc + 2] = p1;
  }
  __syncthreads();   // B0: x1 staged

  floatx4 oacc[12];
  #pragma unroll
  for (int t = 0; t < 12; ++t) oacc[t] = (floatx4){0.f,0.f,0.f,0.f};

  #pragma unroll
  for (int ch = 0; ch < 4; ++ch) {
    ushort_t* sh = (ch & 1) ? s_h1 : s_h0;
    floatx4 hacc[12];
    #pragma unroll
    for (int t = 0; t < 12; ++t) hacc[t] = (floatx4){0.f,0.f,0.f,0.f};
    #pragma unroll
    for (int kt = 0; kt < 6; ++kt) {
      short8 a[4];
      #pragma unroll
      for (int mt = 0; mt < 4; ++mt)
        a[mt] = *(const short8*)&s_a[(mt*16 + l15)*AS2 + kt*32 + quad*8];
      #pragma unroll
      for (int nt = 0; nt < 3; ++nt) {
        int n = ch*192 + wave*48 + nt*16 + l15;
        short8 b = *(const short8*)&w1b[(size_t)n*CDIM + kt*32 + quad*8];
        #pragma unroll
        for (int mt = 0; mt < 4; ++mt)
          hacc[nt*4+mt] = __builtin_amdgcn_mfma_f32_16x16x32_bf16(a[mt], b, hacc[nt*4+mt], 0, 0, 0);
      }
    }
    #pragma unroll
    for (int nt = 0; nt < 3; ++nt) {
      int n = ch*192 + wave*48 + nt*16 + l15;
      int cloc = wave*48 + nt*16 + l15;
      float bias = fc1_b[n];
      #pragma unroll
      for (int mt = 0; mt < 4; ++mt) {
        #pragma unroll
        for (int r = 0; r < 4; ++r) {
          float v = hacc[nt*4+mt][r] + bias;
          sh[(mt*16 + quad*4 + r)*HS2 + cloc] = f2b(gelu_fast(v));
        }
      }
    }
    __syncthreads();   // B(ch): H chunk visible; prev readers of this buf done
    #pragma unroll
    for (int kt = 0; kt < 6; ++kt) {
      short8 a2[4];
      #pragma unroll
      for (int mt = 0; mt < 4; ++mt)
        a2[mt] = *(const short8*)&sh[(mt*16 + l15)*HS2 + kt*32 + quad*8];
      #pragma unroll
      for (int nt = 0; nt < 3; ++nt) {
        int n2 = wave*48 + nt*16 + l15;
        short8 b2 = *(const short8*)&w2b[(size_t)n2*MLPH + ch*192 + kt*32 + quad*8];
        #pragma unroll
        for (int mt = 0; mt < 4; ++mt)
          oacc[nt*4+mt] = __builtin_amdgcn_mfma_f32_16x16x32_bf16(a2[mt], b2, oacc[nt*4+mt], 0, 0, 0);
      }
    }
    // no second barrier: next chunk writes the OTHER buffer
  }

  // O + fc2_b -> s_o (overlay spans s_a+s_h0; in-flight GEMM2(3) reads s_h1)
  #pragma unroll
  for (int nt = 0; nt < 3; ++nt) {
    int c = wave*48 + nt*16 + l15;
    float bb = fc2_b[c];
    #pragma unroll
    for (int mt = 0; mt < 4; ++mt) {
      #pragma unroll
      for (int r = 0; r < 4; ++r)
        s_o[(mt*16 + quad*4 + r)*OS2 + c] = oacc[nt*4+mt][r] + bb;
    }
  }
  __syncthreads();   // B5: s_o complete
  // LN2 stats, wave-parallel: 4 threads/row (64 rows x 4 = 256 threads)
  {
    int row = tid >> 2, part = tid & 3;
    const float4* rp = (const float4*)(s_o + row*OS2) + part*12;
    float mu = 0.f;
    #pragma unroll
    for (int c = 0; c < 12; ++c) { float4 v = rp[c]; mu += v.x+v.y+v.z+v.w; }
    mu += __shfl_xor(mu, 1, 64);
    mu += __shfl_xor(mu, 2, 64);
    mu *= (1.0f/CDIM);
    float var = 0.f;
    #pragma unroll
    for (int c = 0; c < 12; ++c) {
      float4 v = rp[c];
      float a0=v.x-mu, a1=v.y-mu, a2=v.z-mu, a3=v.w-mu;
      var += a0*a0 + a1*a1 + a2*a2 + a3*a3;
    }
    var += __shfl_xor(var, 1, 64);
    var += __shfl_xor(var, 2, 64);
    var *= (1.0f/CDIM);
    if (part == 0) { s_mu[row] = mu; s_rs[row] = rsqrtf(var + 1e-5f); }
  }
  __syncthreads();   // B6
  for (int e = tid; e < 64*48; e += 256) {
    int t = e / 48, cc = (e % 48) * 4;
    float4 xv = *(const float4*)(io + base + t*CDIM + cc);
    float4 wv = *(const float4*)(n2w + cc);
    float4 bv = *(const float4*)(n2b + cc);
    float mu = s_mu[t], rs = s_rs[t];
    float4 o;
    o.x = xv.x + (s_o[t*OS2+cc  ] - mu)*rs*wv.x + bv.x;
    o.y = xv.y + (s_o[t*OS2+cc+1] - mu)*rs*wv.y + bv.y;
    o.z = xv.z + (s_o[t*OS2+cc+2] - mu)*rs*wv.z + bv.z;
    o.w = xv.w + (s_o[t*OS2+cc+3] - mu)*rs*wv.w + bv.w;
    *(float4*)(io + base + t*CDIM + cc) = o;
  }
}

extern "C" void kernel_launch(void* const* d_in, const int* in_sizes, int n_in,
                              void* d_out, int out_size, void* d_ws, size_t ws_size,
                              hipStream_t stream) {
  const float* x           = (const float*)d_in[0];
  const float* qkv_w       = (const float*)d_in[1];
  const float* qkv_b       = (const float*)d_in[2];
  const float* proj_w      = (const float*)d_in[3];
  const float* proj_b      = (const float*)d_in[4];
  const float* logit_scale = (const float*)d_in[5];
  const float* cpb_w1      = (const float*)d_in[6];
  const float* cpb_b1      = (const float*)d_in[7];
  const float* cpb_w2      = (const float*)d_in[8];
  const float* n1w         = (const float*)d_in[9];
  const float* n1b         = (const float*)d_in[10];
  const float* n2w         = (const float*)d_in[11];
  const float* n2b         = (const float*)d_in[12];
  const float* fc1_w       = (const float*)d_in[13];
  const float* fc1_b       = (const float*)d_in[14];
  const float* fc2_w       = (const float*)d_in[15];
  const float* fc2_b       = (const float*)d_in[16];
  float* out = (float*)d_out;

  // workspace layout
  ushort_t* w1b = (ushort_t*)d_ws;            // MLPH*CDIM
  ushort_t* w2b = w1b + MLPH*CDIM;            // CDIM*MLPH
  ushort_t* qwb = w2b + CDIM*MLPH;            // 3*CDIM*CDIM
  ushort_t* pwb = qwb + 3*CDIM*CDIM;          // CDIM*CDIM (col-permuted)
  float* cbias  = (float*)(pwb + CDIM*CDIM);  // 4*6*49*49
  float* bt     = cbias + 4*NHEADS*NTOK*NTOK; // 169*6
  ushort_t* qkvg = (ushort_t*)(bt + 169*NHEADS);  // NTOKENS*576 bf16

  size_t base_b = (size_t)(2*MLPH*CDIM + 4*CDIM*CDIM)*2
                + (size_t)(4*NHEADS*NTOK*NTOK)*4 + (size_t)(169*NHEADS)*4;
  size_t qkvg_b = (size_t)NTOKENS*QKS*2;
  bool split_qkv = ws_size >= base_b + qkvg_b;

  int prep_elems = 2*MLPH*CDIM + 4*CDIM*CDIM;
  hipLaunchKernelGGL(prep_kernel, dim3((prep_elems + 255)/256), dim3(256), 0, stream,
                     fc1_w, fc2_w, qkv_w, proj_w, w1b, w2b, qwb, pwb);
  hipLaunchKernelGGL(cpb1_kernel, dim3((169 + 3)/4), dim3(256), 0, stream,
                     cpb_w1, cpb_b1, cpb_w2, bt);
  hipLaunchKernelGGL(cpb2_kernel, dim3((4*NHEADS*NTOK*NTOK + 255)/256), dim3(256), 0, stream,
                     bt, cbias);
  if (split_qkv) {
    hipLaunchKernelGGL(qkv_kernel, dim3(NTOKENS/64), dim3(384), 0, stream,
                       x, qwb, qkv_b, qkvg);
    hipLaunchKernelGGL(attn_kernel, dim3(2048), dim3(512), 0, stream,
                       x, qkvg, pwb, proj_b, logit_scale, cbias, n1w, n1b, out);
  } else {
    hipLaunchKernelGGL(attn_fused, dim3(2048), dim3(512), 0, stream,
                       x, qwb, qkv_b, pwb, proj_b, logit_scale, cbias, n1w, n1b, out);
  }
  hipLaunchKernelGGL(mlp_kernel, dim3(NTOKENS/64), dim3(256), 0, stream,
                     w1b, w2b, fc1_b, fc2_b, n2w, n2b, out);
}